// Round 2
// baseline (394.753 us; speedup 1.0000x reference)
//
#include <hip/hip_runtime.h>
#include <hip/hip_fp16.h>

#define N_ 4
#define H_ 256
#define W_ 256
#define C_ 96
#define CHB 24     // channels per block (quarter of C_)
#define NFR 6      // scan fragments per wave = CHB/4
#define TP 258     // tile row stride (halves)
#define SP 132     // stage row stride (floats)
#define NFILT 4

__constant__ float c_a[NFILT] = {0.1f, 0.3f, 0.4f, 0.8f};

// Forward scan, 256 positions as lane*4+j. Truncated Kogge-Stone: carry
// multiplier A=a^4<=0.41; omitted terms weigh A^16~6e-7 -> steps {1,2,4,8}.
__device__ __forceinline__ void scan_fwd(float &v0, float &v1, float &v2, float &v3,
                                         float a, int lane) {
  const float b = 1.0f - a;
  const float a2 = a * a, a3 = a2 * a, a4 = a2 * a2;
  float t0 = b * v0;
  float t1 = fmaf(a, t0, b * v1);
  float t2 = fmaf(a, t1, b * v2);
  float t3 = fmaf(a, t2, b * v3);
  if (lane == 0) {  // init carry y_{-1} := x_0  => y_0 = x_0
    t0 = fmaf(a,  v0, t0);
    t1 = fmaf(a2, v0, t1);
    t2 = fmaf(a3, v0, t2);
    t3 = fmaf(a4, v0, t3);
  }
  float c = t3;
  float m = a4;
  #pragma unroll
  for (int d = 1; d <= 8; d <<= 1) {
    float o = __shfl_up(c, (unsigned)d, 64);
    if (lane >= d) c = fmaf(m, o, c);
    m = m * m;
  }
  float cin = __shfl_up(c, 1u, 64);
  if (lane == 0) cin = 0.0f;
  v0 = fmaf(a,  cin, t0);
  v1 = fmaf(a2, cin, t1);
  v2 = fmaf(a3, cin, t2);
  v3 = fmaf(a4, cin, t3);
}

__device__ __forceinline__ void scan_bwd(float &v0, float &v1, float &v2, float &v3,
                                         float a, int lane) {
  const float b = 1.0f - a;
  const float a2 = a * a, a3 = a2 * a, a4 = a2 * a2;
  float t3 = b * v3;
  float t2 = fmaf(a, t3, b * v2);
  float t1 = fmaf(a, t2, b * v1);
  float t0 = fmaf(a, t1, b * v0);
  if (lane == 63) {  // init carry := y_255
    t3 = fmaf(a,  v3, t3);
    t2 = fmaf(a2, v3, t2);
    t1 = fmaf(a3, v3, t1);
    t0 = fmaf(a4, v3, t0);
  }
  float c = t0;
  float m = a4;
  #pragma unroll
  for (int d = 1; d <= 8; d <<= 1) {
    float o = __shfl_down(c, (unsigned)d, 64);
    if (lane < 64 - d) c = fmaf(m, o, c);
    m = m * m;
  }
  float cin = __shfl_down(c, 1u, 64);
  if (lane == 63) cin = 0.0f;
  v3 = fmaf(a,  cin, t3);
  v2 = fmaf(a3 * 0 + a, cin, t3) * 0 + fmaf(a2, cin, t2);  // see note below
  v1 = fmaf(a3, cin, t1);
  v0 = fmaf(a4, cin, t0);
}

// NOTE: the v2 line above must be exactly fmaf(a2, cin, t2); the dead
// arithmetic is folded away by the compiler but to avoid any doubt we
// restate the clean version and use it instead:
__device__ __forceinline__ void scan_bwd_clean(float &v0, float &v1, float &v2, float &v3,
                                               float a, int lane) {
  const float b = 1.0f - a;
  const float a2 = a * a, a3 = a2 * a, a4 = a2 * a2;
  float t3 = b * v3;
  float t2 = fmaf(a, t3, b * v2);
  float t1 = fmaf(a, t2, b * v1);
  float t0 = fmaf(a, t1, b * v0);
  if (lane == 63) {
    t3 = fmaf(a,  v3, t3);
    t2 = fmaf(a2, v3, t2);
    t1 = fmaf(a3, v3, t1);
    t0 = fmaf(a4, v3, t0);
  }
  float c = t0;
  float m = a4;
  #pragma unroll
  for (int d = 1; d <= 8; d <<= 1) {
    float o = __shfl_down(c, (unsigned)d, 64);
    if (lane < 64 - d) c = fmaf(m, o, c);
    m = m * m;
  }
  float cin = __shfl_down(c, 1u, 64);
  if (lane == 63) cin = 0.0f;
  v3 = fmaf(a,  cin, t3);
  v2 = fmaf(a2, cin, t2);
  v1 = fmaf(a3, cin, t1);
  v0 = fmaf(a4, cin, t0);
}

// W-pass: block = (cq) x (n*H+h), cq owns 24 channels. ONE coalesced x read
// -> fp16 LDS tile [c][w] -> per-thread register snapshot (filter-invariant)
// -> per filter: scan in regs, write into double-buffered tile (thread
// overwrites only its own region), ONE barrier, scatter-store 48B/w segments
// to inter[(fi*4+cq)][n][w][h][c24]. Stores of filter fi overlap the scan of
// fi+1; buffer reuse 2 barriers later is safe (lgkm drained at each barrier).
__global__ __launch_bounds__(256, 4)
void k_wpass(const float* __restrict__ x, __half* __restrict__ inter,
             int f_start, int nf) {
  __shared__ __half tile[2][CHB * TP];   // 2 x 12384 B
  const int cq  = blockIdx.x;            // 0..3
  const int row = blockIdx.y;            // n*H_ + h
  const int h   = row & 255;
  const int n   = row >> 8;
  const int c0  = cq * CHB;
  const int t   = threadIdx.x;
  const int wave = t >> 6, lane = t & 63;

  const float* xrow = x + (size_t)row * (W_ * C_) + c0;
  #pragma unroll
  for (int i = 0; i < 6; ++i) {
    int idx = t + i * 256;               // 1536 float4s
    int w = idx / 6, c4 = idx % 6;
    const float4 v = *(const float4*)(xrow + (size_t)w * C_ + 4 * c4);
    tile[0][(4 * c4 + 0) * TP + w] = __float2half(v.x);
    tile[0][(4 * c4 + 1) * TP + w] = __float2half(v.y);
    tile[0][(4 * c4 + 2) * TP + w] = __float2half(v.z);
    tile[0][(4 * c4 + 3) * TP + w] = __float2half(v.w);
  }
  __syncthreads();

  // Snapshot this thread's fragments (identical for every filter).
  float xf[NFR][4];
  #pragma unroll
  for (int ci = 0; ci < NFR; ++ci) {
    const int c = wave + 4 * ci;
    const __half2* p = (const __half2*)(tile[0] + c * TP + 4 * lane);
    float2 f01 = __half22float2(p[0]);
    float2 f23 = __half22float2(p[1]);
    xf[ci][0] = f01.x; xf[ci][1] = f01.y;
    xf[ci][2] = f23.x; xf[ci][3] = f23.y;
  }
  // No barrier needed: each thread's first writeback covers exactly the
  // region it snapshot-read itself.

  for (int fi = 0; fi < nf; ++fi) {
    const float a = c_a[f_start + fi];
    __half* buf = tile[fi & 1];
    #pragma unroll
    for (int ci = 0; ci < NFR; ++ci) {
      float v0 = xf[ci][0], v1 = xf[ci][1], v2 = xf[ci][2], v3 = xf[ci][3];
      scan_fwd(v0, v1, v2, v3, a, lane);
      scan_bwd_clean(v0, v1, v2, v3, a, lane);
      const int c = wave + 4 * ci;
      __half2* p = (__half2*)(buf + c * TP + 4 * lane);
      p[0] = __floats2half2_rn(v0, v1);
      p[1] = __floats2half2_rn(v2, v3);
    }
    __syncthreads();
    // inter[(fi*4+cq)][n] chunk: [w][h][c24], contiguous H*CHB halves per w.
    __half* ibase = inter + (((size_t)(fi * 4 + cq) * (N_ * W_) + (size_t)n * W_)
                             * (H_ * CHB)) + (size_t)h * CHB;
    #pragma unroll
    for (int i = 0; i < 3; ++i) {
      int idx = t + i * 256;             // 768 uint4s
      int w = idx / 3, j = idx % 3;
      union { uint4 u; ushort s[8]; } pk;
      #pragma unroll
      for (int k = 0; k < 8; ++k)
        pk.s[k] = __half_as_ushort(buf[(8 * j + k) * TP + w]);
      *(uint4*)(ibase + (size_t)w * (H_ * CHB) + 8 * j) = pk.u;
    }
  }
}

// H-pass: block = (cq) x (n*W+w), cq owns 24 channels. Per filter: fully
// contiguous 12KB chunk -> 3 uint4 regs (prefetched across filters) -> LDS
// transpose [c][h] -> scan + weighted accumulate in regs -> staged coalesced
// out writes. LDS ~13KB -> 8 blocks/CU (wave cap).
__global__ __launch_bounds__(256, 4)
void k_hpass(const __half* __restrict__ inter, const float* __restrict__ gate,
             float* __restrict__ out, int f_start, int nf, int accumulate) {
  __shared__ __align__(16) unsigned char smem[CHB * SP * 4];  // 12672 B
  __half* tile = (__half*)smem;        // CHB*TP*2 = 12384 B
  float*  stage = (float*)smem;        // CHB*SP*4 (after scans)
  __shared__ float wlds[NFILT * CHB];
  const int cq  = blockIdx.x;          // 0..3
  const int col = blockIdx.y;          // n*W_ + w
  const int n = col >> 8, w = col & 255;
  const int c0 = cq * CHB;
  const int t = threadIdx.x;
  const int wave = t >> 6, lane = t & 63;

  if (t < CHB) {
    const int c = c0 + t;
    float g0 = gate[0 * C_ + c], g1 = gate[1 * C_ + c];
    float g2 = gate[2 * C_ + c], g3 = gate[3 * C_ + c];
    float mx = fmaxf(fmaxf(g0, g1), fmaxf(g2, g3));
    float e0 = __expf(g0 - mx), e1 = __expf(g1 - mx);
    float e2 = __expf(g2 - mx), e3 = __expf(g3 - mx);
    float inv = 1.0f / (e0 + e1 + e2 + e3);
    wlds[0 * CHB + t] = e0 * inv;
    wlds[1 * CHB + t] = e1 * inv;
    wlds[2 * CHB + t] = e2 * inv;
    wlds[3 * CHB + t] = e3 * inv;
  }

  float acc[NFR][4];
  #pragma unroll
  for (int ci = 0; ci < NFR; ++ci)
    acc[ci][0] = acc[ci][1] = acc[ci][2] = acc[ci][3] = 0.0f;

  const size_t chunk = (size_t)H_ * CHB;  // halves per (fi,cq,n,w) chunk
  uint4 pf[3];
  {
    const uint4* src = (const uint4*)(inter +
        ((size_t)(0 * 4 + cq) * (N_ * W_) + (size_t)n * W_ + w) * chunk);
    #pragma unroll
    for (int i = 0; i < 3; ++i) pf[i] = src[i * 256 + t];
  }

  for (int fi = 0; fi < nf; ++fi) {
    __syncthreads();                     // prev scan reads done (and wlds ready)
    #pragma unroll
    for (int i = 0; i < 3; ++i) {
      int e = i * 256 + t;               // 768 uint4s
      int h = e / 3, c8 = e % 3;
      union { uint4 u; ushort s[8]; } pk;
      pk.u = pf[i];
      #pragma unroll
      for (int k = 0; k < 8; ++k)
        tile[(8 * c8 + k) * TP + h] = __ushort_as_half(pk.s[k]);
    }
    __syncthreads();
    if (fi + 1 < nf) {                   // prefetch next filter's chunk
      const uint4* src = (const uint4*)(inter +
          ((size_t)((fi + 1) * 4 + cq) * (N_ * W_) + (size_t)n * W_ + w) * chunk);
      #pragma unroll
      for (int i = 0; i < 3; ++i) pf[i] = src[i * 256 + t];
    }
    const float a = c_a[f_start + fi];
    #pragma unroll
    for (int ci = 0; ci < NFR; ++ci) {
      const int c = wave + 4 * ci;
      const __half2* p = (const __half2*)(tile + c * TP + 4 * lane);
      float2 f01 = __half22float2(p[0]);
      float2 f23 = __half22float2(p[1]);
      float v0 = f01.x, v1 = f01.y, v2 = f23.x, v3 = f23.y;
      scan_fwd(v0, v1, v2, v3, a, lane);
      scan_bwd_clean(v0, v1, v2, v3, a, lane);
      const float wg = wlds[(f_start + fi) * CHB + c];
      acc[ci][0] = fmaf(wg, v0, acc[ci][0]);
      acc[ci][1] = fmaf(wg, v1, acc[ci][1]);
      acc[ci][2] = fmaf(wg, v2, acc[ci][2]);
      acc[ci][3] = fmaf(wg, v3, acc[ci][3]);
    }
  }

  // Output: two half-h rounds through a 12.7KB fp32 stage (reuses tile LDS).
  #pragma unroll
  for (int r = 0; r < 2; ++r) {
    __syncthreads();
    if ((lane >> 5) == r) {
      const int hl = 4 * (lane & 31);
      #pragma unroll
      for (int ci = 0; ci < NFR; ++ci) {
        float4* sp = (float4*)(stage + (wave + 4 * ci) * SP + hl);
        *sp = make_float4(acc[ci][0], acc[ci][1], acc[ci][2], acc[ci][3]);
      }
    }
    __syncthreads();
    float* obase = out + (((size_t)n * H_ + 128 * r) * W_ + w) * C_ + c0;
    #pragma unroll
    for (int i = 0; i < 3; ++i) {
      int idx = t + i * 256;             // 768 float4s per round
      int hl = idx / 6, c4 = idx % 6;
      float4 v;
      v.x = stage[(4 * c4 + 0) * SP + hl];
      v.y = stage[(4 * c4 + 1) * SP + hl];
      v.z = stage[(4 * c4 + 2) * SP + hl];
      v.w = stage[(4 * c4 + 3) * SP + hl];
      float4* dst = (float4*)(obase + (size_t)hl * (W_ * C_) + 4 * c4);
      if (accumulate) {
        float4 pv = *dst;
        v.x += pv.x; v.y += pv.y; v.z += pv.z; v.w += pv.w;
      }
      *dst = v;
    }
  }
}

extern "C" void kernel_launch(void* const* d_in, const int* in_sizes, int n_in,
                              void* d_out, int out_size, void* d_ws, size_t ws_size,
                              hipStream_t stream) {
  const float* x    = (const float*)d_in[0];
  const float* gate = (const float*)d_in[1];
  float* out        = (float*)d_out;
  __half* inter     = (__half*)d_ws;

  const size_t per_f = (size_t)N_ * H_ * W_ * C_ * sizeof(__half);  // 50.3 MB
  int batch = 1;
  if (ws_size >= 4 * per_f)      batch = 4;
  else if (ws_size >= 2 * per_f) batch = 2;

  int done = 0;
  while (done < NFILT) {
    int nf = NFILT - done;
    if (nf > batch) nf = batch;
    dim3 g1(4, N_ * H_);
    k_wpass<<<g1, dim3(256), 0, stream>>>(x, inter, done, nf);
    dim3 g2(4, N_ * W_);
    k_hpass<<<g2, dim3(256), 0, stream>>>(inter, gate, out, done, nf,
                                          done > 0 ? 1 : 0);
    done += nf;
  }
}

// Round 3
// 374.686 us; speedup vs baseline: 1.0536x; 1.0536x over previous
//
#include <hip/hip_runtime.h>
#include <hip/hip_fp16.h>

#define N_ 4
#define H_ 256
#define W_ 256
#define C_ 96
#define CH 48      // channels per block (half of C_)
#define NFR 12     // scan fragments per thread = CH/4
#define TP 258     // tile row stride (halves)
#define SP 132     // stage row stride (floats)
#define NFILT 4

__constant__ float c_a[NFILT] = {0.1f, 0.3f, 0.4f, 0.8f};

// Forward scan, 256 positions as lane*4+j. Truncated Kogge-Stone: carry
// multiplier A=a^4<=0.41; omitted terms weigh A^16~6e-7 -> steps {1,2,4,8}.
__device__ __forceinline__ void scan_fwd(float &v0, float &v1, float &v2, float &v3,
                                         float a, int lane) {
  const float b = 1.0f - a;
  const float a2 = a * a, a3 = a2 * a, a4 = a2 * a2;
  float t0 = b * v0;
  float t1 = fmaf(a, t0, b * v1);
  float t2 = fmaf(a, t1, b * v2);
  float t3 = fmaf(a, t2, b * v3);
  if (lane == 0) {  // init carry y_{-1} := x_0  => y_0 = x_0
    t0 = fmaf(a,  v0, t0);
    t1 = fmaf(a2, v0, t1);
    t2 = fmaf(a3, v0, t2);
    t3 = fmaf(a4, v0, t3);
  }
  float c = t3;
  float m = a4;
  #pragma unroll
  for (int d = 1; d <= 8; d <<= 1) {
    float o = __shfl_up(c, (unsigned)d, 64);
    if (lane >= d) c = fmaf(m, o, c);
    m = m * m;
  }
  float cin = __shfl_up(c, 1u, 64);
  if (lane == 0) cin = 0.0f;
  v0 = fmaf(a,  cin, t0);
  v1 = fmaf(a2, cin, t1);
  v2 = fmaf(a3, cin, t2);
  v3 = fmaf(a4, cin, t3);
}

__device__ __forceinline__ void scan_bwd(float &v0, float &v1, float &v2, float &v3,
                                         float a, int lane) {
  const float b = 1.0f - a;
  const float a2 = a * a, a3 = a2 * a, a4 = a2 * a2;
  float t3 = b * v3;
  float t2 = fmaf(a, t3, b * v2);
  float t1 = fmaf(a, t2, b * v1);
  float t0 = fmaf(a, t1, b * v0);
  if (lane == 63) {  // init carry := y_255
    t3 = fmaf(a,  v3, t3);
    t2 = fmaf(a2, v3, t2);
    t1 = fmaf(a3, v3, t1);
    t0 = fmaf(a4, v3, t0);
  }
  float c = t0;
  float m = a4;
  #pragma unroll
  for (int d = 1; d <= 8; d <<= 1) {
    float o = __shfl_down(c, (unsigned)d, 64);
    if (lane < 64 - d) c = fmaf(m, o, c);
    m = m * m;
  }
  float cin = __shfl_down(c, 1u, 64);
  if (lane == 63) cin = 0.0f;
  v3 = fmaf(a,  cin, t3);
  v2 = fmaf(a2, cin, t2);
  v1 = fmaf(a3, cin, t1);
  v0 = fmaf(a4, cin, t0);
}

// Grid decode: 2048 1D blocks -> (pair, chalf) with chalf-siblings spaced 8
// apart (same XCD under linear%8 round-robin, dispatch-adjacent -> L2 share).
__device__ __forceinline__ void decode_bid(int bid, int &pair, int &chalf) {
  pair  = (bid & 7) | ((bid >> 4) << 3);
  chalf = (bid >> 3) & 1;
}

// W-pass: block = (chalf, row=n*H+h), fused over all nf filters. ONE coalesced
// x read -> fp16 LDS tile [c][w] -> per-thread register snapshot (filter-
// invariant) -> per filter: scan in regs, write back in-place (thread owns its
// region), barrier, repack+store, barrier. Store target is the block's OWN
// 384B-aligned 384B slice of record inter[n][w][h][chalf][fi][c48] -> every
// inter line is written whole by one block (no partial-line RMW at HBM).
__global__ __launch_bounds__(256, 5)
void k_wpass(const float* __restrict__ x, __half* __restrict__ inter,
             int f_start, int nf) {
  __shared__ __half tile[CH * TP];        // 24768 B, single buffer (in-place)
  int row, chalf;
  decode_bid(blockIdx.x, row, chalf);     // row = n*H_ + h
  const int h  = row & 255;
  const int n  = row >> 8;
  const int c0 = chalf * CH;
  const int t  = threadIdx.x;
  const int wave = t >> 6, lane = t & 63;
  const int R  = 2 * nf * CH;             // halves per (w,h) record

  const float* xrow = x + (size_t)row * (W_ * C_) + c0;
  #pragma unroll
  for (int i = 0; i < 12; ++i) {
    int idx = t + i * 256;                // 3072 float4s
    int w = idx / 12, c4 = idx % 12;
    const float4 v = *(const float4*)(xrow + (size_t)w * C_ + 4 * c4);
    tile[(4 * c4 + 0) * TP + w] = __float2half(v.x);
    tile[(4 * c4 + 1) * TP + w] = __float2half(v.y);
    tile[(4 * c4 + 2) * TP + w] = __float2half(v.z);
    tile[(4 * c4 + 3) * TP + w] = __float2half(v.w);
  }
  __syncthreads();

  // Snapshot this thread's fragments (identical for every filter).
  float xf[NFR][4];
  #pragma unroll
  for (int ci = 0; ci < NFR; ++ci) {
    const int c = wave + 4 * ci;
    const __half2* p = (const __half2*)(tile + c * TP + 4 * lane);
    float2 f01 = __half22float2(p[0]);
    float2 f23 = __half22float2(p[1]);
    xf[ci][0] = f01.x; xf[ci][1] = f01.y;
    xf[ci][2] = f23.x; xf[ci][3] = f23.y;
  }
  // No barrier: each thread's first writeback covers exactly the region it
  // snapshot-read itself.

  const size_t hR = (size_t)H_ * R;       // halves per w within a (n) chunk
  for (int fi = 0; fi < nf; ++fi) {
    const float a = c_a[f_start + fi];
    #pragma unroll
    for (int ci = 0; ci < NFR; ++ci) {
      float v0 = xf[ci][0], v1 = xf[ci][1], v2 = xf[ci][2], v3 = xf[ci][3];
      scan_fwd(v0, v1, v2, v3, a, lane);
      scan_bwd(v0, v1, v2, v3, a, lane);
      const int c = wave + 4 * ci;
      __half2* p = (__half2*)(tile + c * TP + 4 * lane);
      p[0] = __floats2half2_rn(v0, v1);
      p[1] = __floats2half2_rn(v2, v3);
    }
    __syncthreads();                      // scan results visible to all
    __half* ib = inter + ((size_t)(n * W_) * H_ + h) * R
                       + (size_t)chalf * nf * CH + (size_t)fi * CH;
    #pragma unroll
    for (int i = 0; i < 6; ++i) {
      int idx = t + i * 256;              // 1536 uint4s
      int w = idx / 6, j = idx % 6;
      union { uint4 u; ushort s[8]; } pk;
      #pragma unroll
      for (int k = 0; k < 8; ++k)
        pk.s[k] = __half_as_ushort(tile[(8 * j + k) * TP + w]);
      *(uint4*)(ib + (size_t)w * hR + 8 * j) = pk.u;
    }
    if (fi + 1 < nf) __syncthreads();     // repack reads done before overwrite
  }
}

// H-pass: block = (chalf, col=n*W+w). Per filter: 96B-per-h strided reads from
// the (n,w) record (fi+1 prefetched; consecutive-fi bytes share lines -> L2
// hit one phase later) -> LDS transpose [c][h] -> scan + weighted accumulate
// in regs -> staged coalesced out writes (chalf-siblings same XCD merge the
// 192B out records).
__global__ __launch_bounds__(256, 4)
void k_hpass(const __half* __restrict__ inter, const float* __restrict__ gate,
             float* __restrict__ out, int f_start, int nf, int accumulate) {
  __shared__ __align__(16) unsigned char smem[CH * SP * 4];  // 25344 B
  __half* tile = (__half*)smem;        // CH*TP*2 = 24768 B
  float*  stage = (float*)smem;        // CH*SP*4 (after scans)
  __shared__ float wlds[NFILT * CH];
  int col, chalf;
  decode_bid(blockIdx.x, col, chalf);  // col = n*W_ + w
  const int n = col >> 8, w = col & 255;
  const int c0 = chalf * CH;
  const int t = threadIdx.x;
  const int wave = t >> 6, lane = t & 63;
  const int R = 2 * nf * CH;           // halves per (w,h) record
  const int hstr = R >> 3;             // uint4s per h record

  if (t < CH) {
    const int c = c0 + t;
    float g0 = gate[0 * C_ + c], g1 = gate[1 * C_ + c];
    float g2 = gate[2 * C_ + c], g3 = gate[3 * C_ + c];
    float mx = fmaxf(fmaxf(g0, g1), fmaxf(g2, g3));
    float e0 = __expf(g0 - mx), e1 = __expf(g1 - mx);
    float e2 = __expf(g2 - mx), e3 = __expf(g3 - mx);
    float inv = 1.0f / (e0 + e1 + e2 + e3);
    wlds[0 * CH + t] = e0 * inv;
    wlds[1 * CH + t] = e1 * inv;
    wlds[2 * CH + t] = e2 * inv;
    wlds[3 * CH + t] = e3 * inv;
  }

  float acc[NFR][4];
  #pragma unroll
  for (int ci = 0; ci < NFR; ++ci)
    acc[ci][0] = acc[ci][1] = acc[ci][2] = acc[ci][3] = 0.0f;

  // Record base for this (n,w,chalf): 6 uint4 per fi per h.
  const uint4* rec = (const uint4*)(inter + ((size_t)(n * W_ + w) * H_) * R
                                          + (size_t)chalf * nf * CH);
  uint4 pf[6];
  #pragma unroll
  for (int i = 0; i < 6; ++i) {
    int e = i * 256 + t;                 // 1536 uint4s for fi=0
    int hh = e / 6, j = e % 6;
    pf[i] = rec[(size_t)hh * hstr + j];
  }

  for (int fi = 0; fi < nf; ++fi) {
    __syncthreads();                     // prev scan reads done (and wlds ready)
    #pragma unroll
    for (int i = 0; i < 6; ++i) {
      int e = i * 256 + t;
      int hh = e / 6, c8 = e % 6;
      union { uint4 u; ushort s[8]; } pk;
      pk.u = pf[i];
      #pragma unroll
      for (int k = 0; k < 8; ++k)
        tile[(8 * c8 + k) * TP + hh] = __ushort_as_half(pk.s[k]);
    }
    __syncthreads();
    if (fi + 1 < nf) {                   // prefetch next filter's columns
      #pragma unroll
      for (int i = 0; i < 6; ++i) {
        int e = i * 256 + t;
        int hh = e / 6, j = e % 6;
        pf[i] = rec[(size_t)hh * hstr + (fi + 1) * 6 + j];
      }
    }
    const float a = c_a[f_start + fi];
    #pragma unroll
    for (int ci = 0; ci < NFR; ++ci) {
      const int c = wave + 4 * ci;
      const __half2* p = (const __half2*)(tile + c * TP + 4 * lane);
      float2 f01 = __half22float2(p[0]);
      float2 f23 = __half22float2(p[1]);
      float v0 = f01.x, v1 = f01.y, v2 = f23.x, v3 = f23.y;
      scan_fwd(v0, v1, v2, v3, a, lane);
      scan_bwd(v0, v1, v2, v3, a, lane);
      const float wg = wlds[(f_start + fi) * CH + c];
      acc[ci][0] = fmaf(wg, v0, acc[ci][0]);
      acc[ci][1] = fmaf(wg, v1, acc[ci][1]);
      acc[ci][2] = fmaf(wg, v2, acc[ci][2]);
      acc[ci][3] = fmaf(wg, v3, acc[ci][3]);
    }
  }

  // Output: two half-h rounds through a 25KB fp32 stage (reuses tile LDS).
  #pragma unroll
  for (int r = 0; r < 2; ++r) {
    __syncthreads();
    if ((lane >> 5) == r) {
      const int hl = 4 * (lane & 31);
      #pragma unroll
      for (int ci = 0; ci < NFR; ++ci) {
        float4* sp = (float4*)(stage + (wave + 4 * ci) * SP + hl);
        *sp = make_float4(acc[ci][0], acc[ci][1], acc[ci][2], acc[ci][3]);
      }
    }
    __syncthreads();
    float* obase = out + (((size_t)n * H_ + 128 * r) * W_ + w) * C_ + c0;
    #pragma unroll
    for (int i = 0; i < 6; ++i) {
      int idx = t + i * 256;             // 1536 float4s per round
      int hl = idx / 12, c4 = idx % 12;
      float4 v;
      v.x = stage[(4 * c4 + 0) * SP + hl];
      v.y = stage[(4 * c4 + 1) * SP + hl];
      v.z = stage[(4 * c4 + 2) * SP + hl];
      v.w = stage[(4 * c4 + 3) * SP + hl];
      float4* dst = (float4*)(obase + (size_t)hl * (W_ * C_) + 4 * c4);
      if (accumulate) {
        float4 pv = *dst;
        v.x += pv.x; v.y += pv.y; v.z += pv.z; v.w += pv.w;
      }
      *dst = v;
    }
  }
}

extern "C" void kernel_launch(void* const* d_in, const int* in_sizes, int n_in,
                              void* d_out, int out_size, void* d_ws, size_t ws_size,
                              hipStream_t stream) {
  const float* x    = (const float*)d_in[0];
  const float* gate = (const float*)d_in[1];
  float* out        = (float*)d_out;
  __half* inter     = (__half*)d_ws;

  const size_t per_f = (size_t)N_ * H_ * W_ * C_ * sizeof(__half);  // 50.3 MB
  int batch = 1;
  if (ws_size >= 4 * per_f)      batch = 4;
  else if (ws_size >= 2 * per_f) batch = 2;

  int done = 0;
  while (done < NFILT) {
    int nf = NFILT - done;
    if (nf > batch) nf = batch;
    k_wpass<<<dim3(2048), dim3(256), 0, stream>>>(x, inter, done, nf);
    k_hpass<<<dim3(2048), dim3(256), 0, stream>>>(inter, gate, out, done, nf,
                                                  done > 0 ? 1 : 0);
    done += nf;
  }
}